// Round 11
// baseline (1051.913 us; speedup 1.0000x reference)
//
#include <hip/hip_runtime.h>
#include <hip/hip_bf16.h>
#include <stdint.h>

#define QMAXF 127.0f

typedef __attribute__((ext_vector_type(4))) float f32x4;
typedef __attribute__((ext_vector_type(4))) int i32x4;

typedef __attribute__((address_space(1))) void gbl_void;
typedef __attribute__((address_space(3))) void lds_void;

__device__ __forceinline__ void gload_lds16(const void* g, void* l) {
    __builtin_amdgcn_global_load_lds((const gbl_void*)g, (lds_void*)l, 16, 0, 0);
}

// ---------------------------------------------------------------------------
// Kernel 1: per-token, per-128-col-group INT8 quant of activations.
// Outputs: q_x int8 [T,K]; scale transposed sxT[kb][T] (f32).
// ---------------------------------------------------------------------------
__global__ __launch_bounds__(256) void qd_x_kernel(const float* __restrict__ x,
                                                   char* __restrict__ qx,
                                                   float* __restrict__ sxT,
                                                   long ngroups, int nkb, int T) {
    long gw = ((long)blockIdx.x * blockDim.x + threadIdx.x) >> 6;
    int lane = threadIdx.x & 63;
    if (gw >= ngroups) return;

    float2 v = *(reinterpret_cast<const float2*>(x) + gw * 64 + lane);
    float a = fmaxf(fabsf(v.x), fabsf(v.y));
#pragma unroll
    for (int off = 32; off; off >>= 1) a = fmaxf(a, __shfl_xor(a, off));

    float scale = a > 0.f ? a / QMAXF : 1.f;
    int q0 = (int)fminf(fmaxf(rintf(v.x / scale), -QMAXF), QMAXF);
    int q1 = (int)fminf(fmaxf(rintf(v.y / scale), -QMAXF), QMAXF);
    unsigned short packed = (unsigned short)((q0 & 0xFF) | ((q1 & 0xFF) << 8));
    reinterpret_cast<unsigned short*>(qx)[gw * 64 + lane] = packed;

    if (lane == 0) {
        int t = (int)(gw / nkb), kb = (int)(gw - (long)t * nkb);
        sxT[(size_t)kb * T + t] = scale;
    }
}

// ---------------------------------------------------------------------------
// Kernel 2: 128x128 blockwise INT8 quant of weights.
// ---------------------------------------------------------------------------
__global__ __launch_bounds__(256) void qd_w_kernel(const float* __restrict__ w,
                                                   char* __restrict__ qw,
                                                   float* __restrict__ sw,
                                                   int K, int nkb) {
    int kb = blockIdx.x, ob = blockIdx.y;
    size_t base = (size_t)ob * 128 * K + (size_t)kb * 128;
    int t = threadIdx.x;

    float4 v[16];
    float a = 0.f;
#pragma unroll
    for (int i = 0; i < 16; i++) {
        int f = i * 256 + t;
        int row = f >> 5, c4 = f & 31;
        v[i] = *reinterpret_cast<const float4*>(w + base + (size_t)row * K + c4 * 4);
        a = fmaxf(a, fmaxf(fmaxf(fabsf(v[i].x), fabsf(v[i].y)),
                           fmaxf(fabsf(v[i].z), fabsf(v[i].w))));
    }
#pragma unroll
    for (int off = 32; off; off >>= 1) a = fmaxf(a, __shfl_xor(a, off));

    __shared__ float red[4];
    if ((t & 63) == 0) red[t >> 6] = a;
    __syncthreads();
    a = fmaxf(fmaxf(red[0], red[1]), fmaxf(red[2], red[3]));

    float scale = a > 0.f ? a / QMAXF : 1.f;
    if (t == 0) sw[(size_t)ob * nkb + kb] = scale;
#pragma unroll
    for (int i = 0; i < 16; i++) {
        int f = i * 256 + t;
        int row = f >> 5, c4 = f & 31;
        int q0 = (int)fminf(fmaxf(rintf(v[i].x / scale), -QMAXF), QMAXF);
        int q1 = (int)fminf(fmaxf(rintf(v[i].y / scale), -QMAXF), QMAXF);
        int q2 = (int)fminf(fmaxf(rintf(v[i].z / scale), -QMAXF), QMAXF);
        int q3 = (int)fminf(fmaxf(rintf(v[i].w / scale), -QMAXF), QMAXF);
        unsigned int p = (q0 & 0xFF) | ((q1 & 0xFF) << 8) | ((q2 & 0xFF) << 16) |
                         ((unsigned int)(q3 & 0xFF) << 24);
        *reinterpret_cast<unsigned int*>(qw + base + (size_t)row * K + c4 * 4) = p;
    }
}

// ---------------------------------------------------------------------------
// Kernel 3: exact INT8 GEMM, 256x256 tile, 8 waves (128x64 wave tile), iter =
// K128 quant group. Issue-first / wait-after counted-lgkm pipeline, sched-
// barrier-pinned load groups (R11 fix), full-tile staging (R10 bug fix:
// 8 gloads/thread = 256 rows of A and B). One s_barrier + one vmcnt(0) per
// iter. sx scales staged to LDS (pure-DS lgkm); sw via lane VGPR + shfl.
// ---------------------------------------------------------------------------
#define A_BY 32768
#define B_BY 32768
#define SX_BY 1024
#define SLOT_BY (A_BY + B_BY + SX_BY)   // 66560

#define BAR()                              \
    do {                                   \
        asm volatile("" ::: "memory");     \
        __builtin_amdgcn_s_barrier();      \
        asm volatile("" ::: "memory");     \
    } while (0)
#define LGKM(n)                                               \
    do {                                                      \
        asm volatile("s_waitcnt lgkmcnt(" #n ")" ::: "memory");\
        __builtin_amdgcn_sched_barrier(0);                    \
    } while (0)
#define WAITV0() asm volatile("s_waitcnt vmcnt(0)" ::: "memory")
#define SCHED0() __builtin_amdgcn_sched_barrier(0)

__global__ __launch_bounds__(512, 1) void gemm_i8_kernel(
    const char* __restrict__ Aq,    // [M,K] int8
    const char* __restrict__ Bq,    // [N,K] int8
    const float* __restrict__ sxT,  // [K/128][M]
    const float* __restrict__ swp,  // [N/128][K/128]
    const float* __restrict__ bias,
    float* __restrict__ C,          // [M,N] f32
    int M, int N, int K) {
    __shared__ alignas(16) unsigned char lds8[2 * SLOT_BY];  // 130 KiB

    int nTm = M >> 8, nTn = N >> 8;
    int nwg = gridDim.x, wg = blockIdx.x;
    int mt, nt;
    int mper = nTm >> 3;
    if ((nTm & 7) == 0 && mper > 0 && (32 % mper) == 0) {
        // XCD-aware 2D window (R5): 32 co-resident blocks/XCD share panels.
        int x = wg & 7, j = wg >> 3;
        int G = 32 / mper;
        int wsz = mper * G;
        int fullw = nTn / G;
        int jfull = fullw * wsz;
        int g, r, width;
        if (j < jfull) { g = j / wsz; r = j - g * wsz; width = G; }
        else { g = fullw; r = j - jfull; width = nTn - fullw * G; }
        mt = x * mper + r / width;
        nt = g * G + r % width;
    } else {
        int swz = (nwg & 7) ? wg : ((wg & 7) * (nwg >> 3) + (wg >> 3));
        mt = swz / nTn; nt = swz - mt * nTn;
    }

    int t = threadIdx.x, wid = t >> 6, lane = t & 63;
    int wm = wid >> 2, wn = wid & 3;   // 2x4 wave grid; wave tile 128x64
    int lr = lane & 15, lq = lane >> 4;
    int nkb = K >> 7;

    const char* Abase = Aq + (size_t)mt * 256 * K;
    const char* Bbase = Bq + (size_t)nt * 256 * K;

    // Staging: tile = 256 rows x 128 B = 2048 chunks of 16 B per matrix;
    // thread t covers chunks t + 512h, h=0..3 (rows t>>3 + 64h; +64 rows
    // preserves row&7, so one swizzled column offset gc0 serves all h).
    // Involution: logical chunk = phys ^ (row & 7).
    int rl0 = t >> 3;
    int gc0 = ((t & 7) ^ (rl0 & 7)) * 16;

    auto STAGE = [&](int slot, int i) {
        size_t kb = (size_t)i << 7;
        unsigned char* sb = lds8 + slot * SLOT_BY;
        const char* ga = Abase + kb + (size_t)rl0 * K + gc0;
        const char* gb = Bbase + kb + (size_t)rl0 * K + gc0;
#pragma unroll
        for (int h = 0; h < 4; h++) {
            gload_lds16(ga + (size_t)(64 * h) * K, sb + (512 * h + t) * 16);
            gload_lds16(gb + (size_t)(64 * h) * K, sb + A_BY + (512 * h + t) * 16);
        }
        if (wid == 0) {  // 1 KB of sx scales for this iter
            const char* gs = (const char*)(sxT + (size_t)i * M + mt * 256 + lane * 4);
            gload_lds16(gs, sb + A_BY + B_BY + lane * 16);
        }
    };

    // Fragment offsets (bytes in slot): row*128 + ((kk*4+lq)^(lr&7))*16.
    int xo0 = ((lq ^ (lr & 7)) << 4);
    int xo1 = (((4 + lq) ^ (lr & 7)) << 4);
    int rowA = wm * 128 + lr;              // + m*16
    int rowB = wn * 64 + lr;               // + n*16
    int sxoff = A_BY + B_BY + (wm * 128 + lq * 4) * 4;  // + m*64

    f32x4 facc[8][4];
#pragma unroll
    for (int m = 0; m < 8; m++)
#pragma unroll
        for (int n = 0; n < 4; n++) facc[m][n] = (f32x4){0.f, 0.f, 0.f, 0.f};

    float swv = (lane < nkb) ? swp[(size_t)(nt * 2 + (wn >> 1)) * nkb + lane] : 0.f;

    i32x4 A0[4], A1[4], b0[4], b1[4];
    f32x4 sxE[2], sxO[2];

    auto RDA = [&](i32x4* dst, const unsigned char* sb, int mp) {
#pragma unroll
        for (int mm = 0; mm < 2; mm++) {
            int rb = (rowA + (mp * 2 + mm) * 16) * 128;
            dst[mm * 2 + 0] = *reinterpret_cast<const i32x4*>(sb + rb + xo0);
            dst[mm * 2 + 1] = *reinterpret_cast<const i32x4*>(sb + rb + xo1);
        }
    };
    auto RDB = [&](i32x4* dst, const unsigned char* sb, int nq) {
#pragma unroll
        for (int nn = 0; nn < 2; nn++) {
            int rb = A_BY + (rowB + (nq * 2 + nn) * 16) * 128;
            dst[nn * 2 + 0] = *reinterpret_cast<const i32x4*>(sb + rb + xo0);
            dst[nn * 2 + 1] = *reinterpret_cast<const i32x4*>(sb + rb + xo1);
        }
    };
    auto RDSX = [&](f32x4* s, const unsigned char* sb, int mp) {
#pragma unroll
        for (int mm = 0; mm < 2; mm++)
            s[mm] = *reinterpret_cast<const f32x4*>(sb + sxoff + (mp * 2 + mm) * 64);
    };
    auto MF = [&](i32x4* Aa, i32x4* Bb, int mp, int nq, f32x4* s, float swq) {
        __builtin_amdgcn_s_setprio(1);
#pragma unroll
        for (int mm = 0; mm < 2; mm++) {
            f32x4 sc = s[mm] * swq;
#pragma unroll
            for (int nn = 0; nn < 2; nn++) {
                i32x4 ia = __builtin_amdgcn_mfma_i32_16x16x64_i8(
                    Aa[mm * 2 + 0], Bb[nn * 2 + 0], (i32x4){0, 0, 0, 0}, 0, 0, 0);
                ia = __builtin_amdgcn_mfma_i32_16x16x64_i8(
                    Aa[mm * 2 + 1], Bb[nn * 2 + 1], ia, 0, 0, 0);
                f32x4& f = facc[mp * 2 + mm][nq * 2 + nn];
#pragma unroll
                for (int r = 0; r < 4; r++) f[r] += (float)ia[r] * sc[r];
            }
        }
        __builtin_amdgcn_s_setprio(0);
    };

    // Prologue: stage iter 0 into slot 0.
    STAGE(0, 0);
    WAITV0();
    BAR();

    for (int i = 0; i < nkb; ++i) {
        const unsigned char* sb = lds8 + (i & 1) * SLOT_BY;
        float swq = __shfl(swv, i);

        // ph1: G1={sx0, A(mp0), b0, b1} (10 ds) | G2={A(mp1)} (4 ds)
        RDSX(sxE, sb, 0);
        RDA(A0, sb, 0);
        RDB(b0, sb, 0);
        RDB(b1, sb, 1);
        SCHED0();
        RDA(A1, sb, 1);
        LGKM(4);                      // G1 done; G2 flies
        MF(A0, b0, 0, 0, sxE, swq);
        // ph2: G3={sx1} (2 ds); stage iter i+1 (vmcnt, flies to iter end)
        SCHED0();
        RDSX(sxO, sb, 1);
        if (i + 1 < nkb) STAGE((i + 1) & 1, i + 1);
        SCHED0();
        MF(A0, b1, 0, 1, sxE, swq);
        // ph3: G4={A(mp2)} (4 ds); wait drains G2+G3, leaves G4
        SCHED0();
        RDA(A0, sb, 2);
        LGKM(4);
        MF(A1, b1, 1, 1, sxO, swq);
        // ph4: G5={sx2} (2 ds)
        SCHED0();
        RDSX(sxE, sb, 2);
        SCHED0();
        MF(A1, b0, 1, 0, sxO, swq);
        // ph5: G6={A(mp3)} (4 ds); wait drains G4+G5, leaves G6
        SCHED0();
        RDA(A1, sb, 3);
        LGKM(4);
        MF(A0, b0, 2, 0, sxE, swq);
        // ph6: G7={sx3} (2 ds)
        SCHED0();
        RDSX(sxO, sb, 3);
        SCHED0();
        MF(A0, b1, 2, 1, sxE, swq);
        // ph7: drain all ds
        LGKM(0);
        MF(A1, b1, 3, 1, sxO, swq);
        // ph8: last quadrant; drain stage; barrier
        MF(A1, b0, 3, 0, sxO, swq);
        WAITV0();
        BAR();
    }

    // Epilogue: bias + store. C/D layout: col = lane&15, row = (lane>>4)*4 + reg.
    float bvv[4];
#pragma unroll
    for (int n = 0; n < 4; n++) bvv[n] = bias[nt * 256 + wn * 64 + n * 16 + lr];

#pragma unroll
    for (int m = 0; m < 8; m++) {
#pragma unroll
        for (int r = 0; r < 4; r++) {
            size_t row = (size_t)(mt * 256 + wm * 128 + m * 16 + lq * 4 + r);
            float* Crow = C + row * N + nt * 256 + wn * 64 + lr;
#pragma unroll
            for (int n = 0; n < 4; n++) Crow[n * 16] = facc[m][n][r] + bvv[n];
        }
    }
}

extern "C" void kernel_launch(void* const* d_in, const int* in_sizes, int n_in,
                              void* d_out, int out_size, void* d_ws, size_t ws_size,
                              hipStream_t stream) {
    const float* x = (const float*)d_in[0];
    const float* w = (const float*)d_in[1];
    const float* bias = (const float*)d_in[2];
    float* y = (float*)d_out;

    int O = in_sizes[2];          // 11008
    int K = in_sizes[1] / O;      // 4096
    int T = in_sizes[0] / K;      // 8192 tokens
    int nkb = K / 128;            // 32

    char* qx = (char*)d_ws;
    size_t off = ((size_t)T * K + 255) & ~(size_t)255;
    char* qw = (char*)d_ws + off;
    off += ((size_t)O * K + 255) & ~(size_t)255;
    float* sxT = (float*)((char*)d_ws + off);
    off += ((size_t)nkb * T * 4 + 255) & ~(size_t)255;
    float* sw = (float*)((char*)d_ws + off);

    long ngroups = (long)T * nkb;
    qd_x_kernel<<<dim3((unsigned)((ngroups + 3) / 4)), dim3(256), 0, stream>>>(
        x, qx, sxT, ngroups, nkb, T);
    qd_w_kernel<<<dim3(nkb, O / 128), dim3(256), 0, stream>>>(w, qw, sw, K, nkb);

    int grid = (T / 256) * (O / 256);
    gemm_i8_kernel<<<dim3(grid), dim3(512), 0, stream>>>(qx, qw, sxT, sw, bias, y,
                                                         T, O, K);
}